// Round 8
// baseline (85.990 us; speedup 1.0000x reference)
//
#include <hip/hip_runtime.h>
#include <math.h>

#define N_ATOMS 512
#define MAX_B 128
#define NREP 8           // replicated global histograms
#define SCALE 1048576.0f // 2^20 fixed-point weight scale
#define INV_SCALE 9.5367431640625e-07f

// ---------------- main kernel ----------------
// Grid: F*128 = 2048 blocks, 256 threads (8 blocks/CU resident).
// Block = (frame, 2 bow-tie row-pairs) = 1024 pairs. Each pair scatters a
// fixed 7-bin +-3sigma Gaussian window into an LDS fixed-point histogram via
// native ds_add_u32 (branch-free: invalid pairs add 0 to per-lane dump slots).
// Tail: fence-free device-scope fp32 atomics into NREP replicated hists,
// ticket, last block atomic-reads and writes outputs. Block 0 writes r_list.
__global__ __launch_bounds__(256) void rdf_onepass(
    const float* __restrict__ traj, const float* __restrict__ cell,
    const float* __restrict__ r_list, float* __restrict__ hist,
    unsigned int* __restrict__ counter, float* __restrict__ out,
    int B, int F, int fused)
{
    __shared__ float qx[N_ATOMS], qy[N_ATOMS], qz[N_ATOMS];
    __shared__ unsigned int shist[MAX_B + 64];   // 128 bins + 64 dump slots
    __shared__ unsigned int ticket;

    const int frame = blockIdx.x >> 7;
    const int sub   = blockIdx.x & 127;
    const int tid   = threadIdx.x;

    const float* q = traj + (size_t)frame * (N_ATOMS * 3);
    for (int a = tid; a < N_ATOMS; a += 256) {
        qx[a] = q[3 * a + 0];
        qy[a] = q[3 * a + 1];
        qz[a] = q[3 * a + 2];
    }
    if (tid < MAX_B + 64) shist[tid] = 0u;
    __syncthreads();

    const float L = cell[0];
    const float invL = 1.0f / L;
    const float cutoff_sq = 0.25f * L * L;
    const float r0 = r_list[0];                  // 0.05
    const unsigned int dump = MAX_B + (tid & 63);

    // block 0: write output 0 (r_list) early, overlapped with compute
    if (blockIdx.x == 0 && tid < B) out[tid] = r_list[tid];

    #pragma unroll
    for (int s = 0; s < 4; ++s) {
        const int qidx = s * 256 + tid;            // [0, 1024)
        const int rp   = sub * 2 + (qidx >> 9);    // row-pair [0, 256)
        const int qq   = qidx & 511;
        const bool inA = qq < (511 - rp);          // row rp: j in (rp, 511]
        const int i = inA ? rp : (510 - rp);       // partner row 510-rp
        const int j = inA ? (rp + 1 + qq) : qq;
        const bool vp = !(rp == 255 && !inA);      // self-paired middle row: half

        float dx = qx[j] - qx[i];
        float dy = qy[j] - qy[i];
        float dz = qz[j] - qz[i];
        dx -= L * floorf(dx * invL + 0.5f);
        dy -= L * floorf(dy * invL + 0.5f);
        dz -= L * floorf(dz * invL + 0.5f);
        const float d2 = dx * dx + dy * dy + dz * dz;

        const bool valid = vp && (d2 < cutoff_sq) && (d2 != 0.0f);
        const float d = sqrtf(d2);
        // bin-space position; invalid lanes pushed far out -> exp underflows to 0
        const float x = valid ? (d - r0) * 10.0f : 3.0e9f;
        const float k0f = ceilf(x - 3.0f);
        const int   k0  = (int)k0f;
        float u = x - k0f;                         // in [2,3)
        int   k = k0;
        #pragma unroll
        for (int t = 0; t < 7; ++t) {
            const float w = __expf(-0.5f * u * u);
            const unsigned int iw = (unsigned int)(fmaf(w, SCALE, 0.5f));
            const unsigned int kc = ((unsigned int)k < (unsigned int)B)
                                        ? (unsigned int)k : dump;
            atomicAdd(&shist[kc], iw);             // native ds_add_u32
            u -= 1.0f;
            k += 1;
        }
    }
    __syncthreads();

    // ---- replicated global hist accumulate (fence-free device atomics) ----
    if (tid < MAX_B)
        unsafeAtomicAdd(&hist[(blockIdx.x & (NREP - 1)) * MAX_B + tid],
                        (float)shist[tid] * INV_SCALE);

    if (!fused) return;

    // ---- ticket (no fence; __syncthreads drains vmcnt, atomics are at the
    //      device coherence point) ----
    __syncthreads();
    if (tid == 0) ticket = atomicAdd(counter, 1u);
    __syncthreads();
    if (ticket != (unsigned)(gridDim.x - 1)) return;

    // ---- last block: atomic-read the NREPx128 hist + write gr ----
    if (tid < B) {
        float h = 0.0f;
        #pragma unroll
        for (int rep = 0; rep < NREP; ++rep)
            h += unsafeAtomicAdd(&hist[rep * MAX_B + tid], 0.0f);  // atomic read
        const float r = r_list[tid];
        const float det = cell[0] * cell[4] * cell[8];
        const float rp_ = r + 0.05f;
        const float rm_ = r - 0.05f;
        const float vsh = (4.0f * (float)M_PI / 3.0f) *
                          (rp_ * rp_ * rp_ - rm_ * rm_ * rm_);
        const float hh = h * 0.3989422804014327f / (float)F;
        out[B + tid] = hh / vsh * det /
                       (float)(N_ATOMS - 1) / (float)N_ATOMS * 2.0f;   // output 1
    }
}

// ---------------- fallback path (tiny ws): 3 dispatches ----------------
__global__ void zero_kernel(float* p, int n) {
    int t = blockIdx.x * blockDim.x + threadIdx.x;
    if (t < n) p[t] = 0.0f;
}

__global__ __launch_bounds__(256) void finalize_kernel(
    const float* __restrict__ r_list, const float* __restrict__ cell,
    const float* __restrict__ hist, float* __restrict__ out, int B, int F)
{
    const int k = blockIdx.x * blockDim.x + threadIdx.x;
    if (k >= B) return;
    float h = 0.0f;
    for (int rep = 0; rep < NREP; ++rep) h += hist[rep * MAX_B + k];
    const float r = r_list[k];
    out[k] = r;
    const float det = cell[0] * cell[4] * cell[8];
    const float rp = r + 0.05f, rm = r - 0.05f;
    const float v = (4.0f * (float)M_PI / 3.0f) * (rp*rp*rp - rm*rm*rm);
    h = h * 0.3989422804014327f / (float)F;
    out[B + k] = h / v * det / (float)(N_ATOMS - 1) / (float)N_ATOMS * 2.0f;
}

extern "C" void kernel_launch(void* const* d_in, const int* in_sizes, int n_in,
                              void* d_out, int out_size, void* d_ws, size_t ws_size,
                              hipStream_t stream) {
    const float* traj   = (const float*)d_in[0];
    const float* cell   = (const float*)d_in[1];
    const float* r_list = (const float*)d_in[2];
    float* out = (float*)d_out;

    int B = in_sizes[2];
    int F = in_sizes[0] / (N_ATOMS * 3);
    int nblk = F * 128;

    const size_t hist_bytes = (size_t)NREP * MAX_B * sizeof(float);

    if (ws_size >= hist_bytes + sizeof(unsigned int)) {
        float* hist = (float*)d_ws;
        unsigned int* counter = (unsigned int*)((char*)d_ws + hist_bytes);
        hipMemsetAsync(d_ws, 0, hist_bytes + sizeof(unsigned int), stream);
        hipLaunchKernelGGL(rdf_onepass, dim3(nblk), dim3(256), 0, stream,
                           traj, cell, r_list, hist, counter, out, B, F, 1);
    } else {
        float* hist = (float*)d_ws;   // needs NREP*MAX_B floats
        hipLaunchKernelGGL(zero_kernel, dim3(4), dim3(256), 0, stream,
                           hist, NREP * MAX_B);
        hipLaunchKernelGGL(rdf_onepass, dim3(nblk), dim3(256), 0, stream,
                           traj, cell, r_list, hist, (unsigned int*)nullptr,
                           out, B, F, 0);
        hipLaunchKernelGGL(finalize_kernel, dim3(1), dim3(MAX_B), 0, stream,
                           r_list, cell, hist, out, B, F);
    }
}